// Round 5
// baseline (3342.041 us; speedup 1.0000x reference)
//
#include <hip/hip_runtime.h>
#include <stdint.h>

// Problem constants
#define VOCAB 50000
#define EMBD  128
#define HID   256
#define G4    1024   // 4*HID
#define BATCH 256
#define TSEQ  512
#define OUTD  64

typedef __attribute__((ext_vector_type(4))) float f32x4;
typedef __attribute__((ext_vector_type(8))) short short8;
typedef __attribute__((ext_vector_type(4))) unsigned short ushort4_t;

__device__ inline unsigned short f2bf(float f) {
  unsigned u = __float_as_uint(f);
  u += 0x7fffu + ((u >> 16) & 1u);     // round-nearest-even
  return (unsigned short)(u >> 16);
}
__device__ inline float bf2f(unsigned short u) {
  return __uint_as_float(((unsigned)u) << 16);
}
__device__ inline short8 pack2(f32x4 a, f32x4 b) {
  short8 r;
  r[0] = (short)f2bf(a[0]); r[1] = (short)f2bf(a[1]);
  r[2] = (short)f2bf(a[2]); r[3] = (short)f2bf(a[3]);
  r[4] = (short)f2bf(b[0]); r[5] = (short)f2bf(b[1]);
  r[6] = (short)f2bf(b[2]); r[7] = (short)f2bf(b[3]);
  return r;
}
__device__ inline float sigmoid_(float x) {
  return __builtin_amdgcn_rcpf(1.0f + __expf(-x));
}
__device__ inline float tanh_(float x) {
  float e = __expf(2.0f * x);
  return (e - 1.0f) * __builtin_amdgcn_rcpf(e + 1.0f);
}

// Wx layout: Wx[v][u*4 + nt], u = h-unit 0..255, nt in {i,f,g,o}; oj = nt*256+u.

// ---------------------------------------------------------------------------
// K1: Wx[v][u*4+nt] = bf16( b_ih[oj] + b_hh[oj] + emb[v] . W_ih[oj] )
// ---------------------------------------------------------------------------
__global__ __launch_bounds__(256) void wx_k1(
    const float* __restrict__ emb, const float* __restrict__ Wih,
    const float* __restrict__ bih, const float* __restrict__ bhh,
    unsigned short* __restrict__ Wx) {
  const int vb = blockIdx.x * 16;
  const int w1 = threadIdx.x >> 6, lane = threadIdx.x & 63;
  const int quad = lane >> 4, n = lane & 15;
  const int combo = blockIdx.y * 4 + w1;        // 0..15 -> units combo*16..+15

  float bias[4];
  short8 bfr[4][4];
#pragma unroll
  for (int nt = 0; nt < 4; ++nt) {
    const int oj = nt * 256 + combo * 16 + n;
    bias[nt] = bih[oj] + bhh[oj];
#pragma unroll
    for (int kc = 0; kc < 4; ++kc) {
      const f32x4* wp = (const f32x4*)(Wih + (size_t)oj * EMBD + kc * 32 + quad * 8);
      bfr[nt][kc] = pack2(wp[0], wp[1]);
    }
  }
  short8 af[4];
#pragma unroll
  for (int kc = 0; kc < 4; ++kc) {
    const f32x4* ep = (const f32x4*)(emb + (size_t)(vb + n) * EMBD + kc * 32 + quad * 8);
    af[kc] = pack2(ep[0], ep[1]);
  }
  f32x4 acc[4];
#pragma unroll
  for (int nt = 0; nt < 4; ++nt) acc[nt] = (f32x4){0.f, 0.f, 0.f, 0.f};
#pragma unroll
  for (int kc = 0; kc < 4; ++kc)
#pragma unroll
    for (int nt = 0; nt < 4; ++nt)
      acc[nt] = __builtin_amdgcn_mfma_f32_16x16x32_bf16(af[kc], bfr[nt][kc], acc[nt], 0, 0, 0);
#pragma unroll
  for (int rr = 0; rr < 4; ++rr) {
    ushort4_t o;
#pragma unroll
    for (int nt = 0; nt < 4; ++nt) o[nt] = f2bf(acc[nt][rr] + bias[nt]);
    *(ushort4_t*)&Wx[(size_t)(vb + quad * 4 + rr) * G4 + (combo * 16 + n) * 4] = o;
  }
}

// ---------------------------------------------------------------------------
// K2: 32 WGs x 512 threads. Pair (wg, wg^16) = 16 batch rows; each WG owns
// 128 h-units (half). Same-XCD pair (wg%8 == (wg^16)%8) -> exchange via L2.
// Per wave: 16 units, B-frags bfr[4][8] = 128 VGPRs, constant-indexed (ha is
// wave-uniform -> branch, never a register-array index; round-1 lesson).
// Publish: post-barrier coalesced 8B copy-out + per-wave release flag.
// Consume: ballot-poll 8 flags + acquire fence + dwordx4 A-frag loads.
// ---------------------------------------------------------------------------
__global__ __launch_bounds__(512, 2) void lstm_k2(
    const int* __restrict__ x, const float* __restrict__ Whh,
    const unsigned short* __restrict__ Wx,
    unsigned long long* __restrict__ hx64,     // [32][2][16][128] bf16 = [32][1024] ULL
    int* __restrict__ flags,                   // [32][8]
    float* __restrict__ lastH) {               // [256][256]
  const int wg = blockIdx.x;
  const int pair = wg & 15, ha = wg >> 4;
  const int partner = wg ^ 16;
  const int rowbase = pair * 16;
  const int tid = threadIdx.x;
  const int w = tid >> 6, lane = tid & 63;
  const int quad = lane >> 4, n = lane & 15;
  const int ul = w * 16 + n;          // local unit 0..127
  const int u  = ha * 128 + ul;       // global unit

  // own-half h double-buffer, row-major [row][unit_local]; stride 136 ush =
  // 68 dw == 4 mod 32 -> 2-way-max bank aliasing (free) for b128 A-reads.
  __shared__ __attribute__((aligned(16))) unsigned short h_lds[2][16][136];
  __shared__ int zpos[16];

  if (tid < 16) zpos[tid] = 1 << 30;
  __syncthreads();
  for (int i = tid; i < 16 * TSEQ; i += 512) {
    const int row = i >> 9, tc = i & 511;
    if (x[(size_t)(rowbase + row) * TSEQ + tc] == 0) atomicMin(&zpos[row], tc);
  }

  // B-frags for this wave's 16 units, all 8 K-chunks: B[k][col=n]=Whh[oj][k]
  short8 bfr[4][8];
#pragma unroll
  for (int nt = 0; nt < 4; ++nt) {
    const int oj = nt * 256 + u;
    const float* wrow = Whh + (size_t)oj * HID;
#pragma unroll
    for (int kc = 0; kc < 8; ++kc) {
      const f32x4* wp = (const f32x4*)(wrow + kc * 32 + quad * 8);
      bfr[nt][kc] = pack2(wp[0], wp[1]);
    }
  }

  float cst[4] = {0.f, 0.f, 0.f, 0.f};
  float lastreg[4] = {0.f, 0.f, 0.f, 0.f};
  __syncthreads();   // zpos ready
  int idx4[4];
#pragma unroll
  for (int rr = 0; rr < 4; ++rr) idx4[rr] = zpos[quad * 4 + rr] - 1;

  // initial Wx load (t=0) + token prefetch for t=1
  ushort4_t wxbuf[4];
  int tokc[4];
#pragma unroll
  for (int rr = 0; rr < 4; ++rr) {
    const int t0 = x[(size_t)(rowbase + quad * 4 + rr) * TSEQ + 0];
    wxbuf[rr] = *(const ushort4_t*)(Wx + (size_t)t0 * G4 + u * 4);
    tokc[rr] = x[(size_t)(rowbase + quad * 4 + rr) * TSEQ + 1];
  }

  unsigned long long* obuf = hx64 + (size_t)wg * 1024;        // [2][512] ULL
  const unsigned short* pbuf = (const unsigned short*)(hx64 + (size_t)partner * 1024);
  int* myflag = flags + wg * 8;
  const int* pflag = flags + partner * 8;

  for (int t = 0; t < TSEQ; ++t) {
    const int p = t & 1, pn = p ^ 1;

    // acc init from prefetched Wx (includes both biases)
    f32x4 acc[4];
#pragma unroll
    for (int rr = 0; rr < 4; ++rr) {
      const ushort4_t g4 = wxbuf[rr];
#pragma unroll
      for (int nt = 0; nt < 4; ++nt) acc[nt][rr] = bf2f(g4[nt]);
    }
    // re-issue Wx prefetch for t+1 (token prefetched last step)
#pragma unroll
    for (int rr = 0; rr < 4; ++rr)
      wxbuf[rr] = *(const ushort4_t*)(Wx + (size_t)tokc[rr] * G4 + u * 4);

    if (t > 0) {
      if (ha == 0) {
        // own half = global K-chunks 0..3, from LDS
#pragma unroll
        for (int kc = 0; kc < 4; ++kc) {
          const short8 a = *(const short8*)&h_lds[p][n][kc * 32 + quad * 8];
#pragma unroll
          for (int nt = 0; nt < 4; ++nt)
            acc[nt] = __builtin_amdgcn_mfma_f32_16x16x32_bf16(a, bfr[nt][kc], acc[nt], 0, 0, 0);
        }
        // wait for partner h(t), then partner half = K-chunks 4..7 from L2
        for (;;) {
          const int f = __hip_atomic_load(&pflag[lane & 7], __ATOMIC_RELAXED,
                                          __HIP_MEMORY_SCOPE_AGENT);
          if (__ballot((lane < 8) ? (f >= t) : 1) == ~0ull) break;
        }
        __builtin_amdgcn_fence(__ATOMIC_ACQUIRE, "agent");
#pragma unroll
        for (int kc = 0; kc < 4; ++kc) {
          const short8 a = *(const short8*)&pbuf[p * 2048 + n * 128 + kc * 32 + quad * 8];
#pragma unroll
          for (int nt = 0; nt < 4; ++nt)
            acc[nt] = __builtin_amdgcn_mfma_f32_16x16x32_bf16(a, bfr[nt][4 + kc], acc[nt], 0, 0, 0);
        }
      } else {
        // own half = global K-chunks 4..7, from LDS
#pragma unroll
        for (int kc = 0; kc < 4; ++kc) {
          const short8 a = *(const short8*)&h_lds[p][n][kc * 32 + quad * 8];
#pragma unroll
          for (int nt = 0; nt < 4; ++nt)
            acc[nt] = __builtin_amdgcn_mfma_f32_16x16x32_bf16(a, bfr[nt][4 + kc], acc[nt], 0, 0, 0);
        }
        for (;;) {
          const int f = __hip_atomic_load(&pflag[lane & 7], __ATOMIC_RELAXED,
                                          __HIP_MEMORY_SCOPE_AGENT);
          if (__ballot((lane < 8) ? (f >= t) : 1) == ~0ull) break;
        }
        __builtin_amdgcn_fence(__ATOMIC_ACQUIRE, "agent");
#pragma unroll
        for (int kc = 0; kc < 4; ++kc) {
          const short8 a = *(const short8*)&pbuf[p * 2048 + n * 128 + kc * 32 + quad * 8];
#pragma unroll
          for (int nt = 0; nt < 4; ++nt)
            acc[nt] = __builtin_amdgcn_mfma_f32_16x16x32_bf16(a, bfr[nt][kc], acc[nt], 0, 0, 0);
        }
      }
    }

    // pointwise: lane owns unit u for rows quad*4+rr; acc[nt] = i,f,g,o
#pragma unroll
    for (int rr = 0; rr < 4; ++rr) {
      const float gi = acc[0][rr], gf = acc[1][rr], gg = acc[2][rr], go = acc[3][rr];
      const float ci = sigmoid_(gf) * cst[rr] + sigmoid_(gi) * tanh_(gg);
      cst[rr] = ci;
      const float hv = sigmoid_(go) * tanh_(ci);
      lastreg[rr] = (t == idx4[rr]) ? hv : lastreg[rr];
      h_lds[pn][quad * 4 + rr][ul] = f2bf(hv);
    }
    // token prefetch for t+2
    {
      const int tnn = (t + 2 < TSEQ) ? (t + 2) : (TSEQ - 1);
#pragma unroll
      for (int rr = 0; rr < 4; ++rr)
        tokc[rr] = x[(size_t)(rowbase + quad * 4 + rr) * TSEQ + tnn];
    }

    __syncthreads();  // h_lds[pn] complete (all waves)

    if (t < TSEQ - 1) {
      // coalesced copy-out of own half h(t+1): 8B/thread, row-major
      const int row = tid >> 5, cu = (tid & 31) * 4;
      const unsigned long long v = *(const unsigned long long*)&h_lds[pn][row][cu];
      __hip_atomic_store(&obuf[pn * 512 + (tid & 511)], v,
                         __ATOMIC_RELAXED, __HIP_MEMORY_SCOPE_AGENT);
      // wait: obuf layout must be [pn][row][unit] ULL-indexed = row*32 + cu/4
      // (tid = row*32 + (tid&31), cu/4 = tid&31 -> obuf[pn*512 + tid]) ✓
      if (lane == 0)
        __hip_atomic_store(&myflag[w], t + 1, __ATOMIC_RELEASE,
                           __HIP_MEMORY_SCOPE_AGENT);
    }
  }

  // final: write gathered last-valid h (f32)
#pragma unroll
  for (int rr = 0; rr < 4; ++rr)
    lastH[(size_t)(rowbase + quad * 4 + rr) * HID + u] = lastreg[rr];
}

// ---------------------------------------------------------------------------
// K3: logits + softmax. One wave per batch row; lane j = output j.
// ---------------------------------------------------------------------------
__global__ __launch_bounds__(64) void head_k3(
    const float* __restrict__ lastH, const float* __restrict__ Wout,
    const float* __restrict__ bout, float* __restrict__ out) {
  const int b = blockIdx.x, j = threadIdx.x;
  const f32x4* hv = (const f32x4*)(lastH + (size_t)b * HID);
  const f32x4* wv = (const f32x4*)(Wout + (size_t)j * HID);
  float acc = bout[j];
#pragma unroll 8
  for (int k = 0; k < HID / 4; ++k) {
    const f32x4 a = hv[k], ww = wv[k];
    acc += a[0] * ww[0] + a[1] * ww[1] + a[2] * ww[2] + a[3] * ww[3];
  }
  float m = acc;
  for (int s = 32; s > 0; s >>= 1) m = fmaxf(m, __shfl_xor(m, s, 64));
  const float e = __expf(acc - m);
  float ssum = e;
  for (int s = 32; s > 0; s >>= 1) ssum += __shfl_xor(ssum, s, 64);
  out[(size_t)b * OUTD + j] = e / ssum;
}

// ---------------------------------------------------------------------------
extern "C" void kernel_launch(void* const* d_in, const int* in_sizes, int n_in,
                              void* d_out, int out_size, void* d_ws, size_t ws_size,
                              hipStream_t stream) {
  const int*   x    = (const int*)d_in[0];
  const float* emb  = (const float*)d_in[1];
  const float* Wih  = (const float*)d_in[2];
  const float* Whh  = (const float*)d_in[3];
  const float* bih  = (const float*)d_in[4];
  const float* bhh  = (const float*)d_in[5];
  const float* Wout = (const float*)d_in[6];
  const float* bout = (const float*)d_in[7];
  float* out = (float*)d_out;

  // workspace carve (~98.3 MiB)
  char* ws = (char*)d_ws;
  unsigned short* Wx = (unsigned short*)ws;                         // 102,400,000 B
  unsigned long long* hx64 = (unsigned long long*)(ws + 102400000); // 262,144 B
  int* flags = (int*)(ws + 102400000 + 262144);                     // 1,024 B
  float* lastH = (float*)(ws + 102400000 + 262144 + 1024);          // 262,144 B

  // flags must start < 1 regardless of workspace poison
  hipMemsetAsync(flags, 0, 32 * 8 * sizeof(int), stream);

  hipLaunchKernelGGL(wx_k1, dim3(3125, 4), dim3(256), 0, stream,
                     emb, Wih, bih, bhh, Wx);
  hipLaunchKernelGGL(lstm_k2, dim3(32), dim3(512), 0, stream,
                     x, Whh, Wx, hx64, flags, lastH);
  hipLaunchKernelGGL(head_k3, dim3(BATCH), dim3(OUTD), 0, stream,
                     lastH, Wout, bout, out);
}

// Round 6
// 2213.436 us; speedup vs baseline: 1.5099x; 1.5099x over previous
//
#include <hip/hip_runtime.h>
#include <stdint.h>

// Problem constants
#define VOCAB 50000
#define EMBD  128
#define HID   256
#define G4    1024   // 4*HID
#define BATCH 256
#define TSEQ  512
#define OUTD  64

typedef __attribute__((ext_vector_type(4))) float f32x4;
typedef __attribute__((ext_vector_type(8))) short short8;
typedef __attribute__((ext_vector_type(4))) unsigned short ushort4_t;

__device__ inline unsigned short f2bf(float f) {
  unsigned u = __float_as_uint(f);
  u += 0x7fffu + ((u >> 16) & 1u);     // round-nearest-even
  return (unsigned short)(u >> 16);
}
__device__ inline float bf2f(unsigned short u) {
  return __uint_as_float(((unsigned)u) << 16);
}
__device__ inline short8 pack2(f32x4 a, f32x4 b) {
  short8 r;
  r[0] = (short)f2bf(a[0]); r[1] = (short)f2bf(a[1]);
  r[2] = (short)f2bf(a[2]); r[3] = (short)f2bf(a[3]);
  r[4] = (short)f2bf(b[0]); r[5] = (short)f2bf(b[1]);
  r[6] = (short)f2bf(b[2]); r[7] = (short)f2bf(b[3]);
  return r;
}
__device__ inline float sigmoid_(float x) {
  return __builtin_amdgcn_rcpf(1.0f + __expf(-x));
}
__device__ inline float tanh_(float x) {
  float e = __expf(2.0f * x);
  return (e - 1.0f) * __builtin_amdgcn_rcpf(e + 1.0f);
}

// LDS-only barrier: __syncthreads() emits s_waitcnt vmcnt(0) lgkmcnt(0) before
// s_barrier, draining our wave-private Wx/token prefetch loads every step and
// exposing HBM gather latency (~1-2.5K cyc/step). The h double-buffer only
// needs LDS ordering -> wait lgkmcnt(0) only; in-flight global loads keep
// their vmcnt wait at point of use (next step), preserving the overlap.
__device__ inline void barrier_lds_only() {
  asm volatile("s_waitcnt lgkmcnt(0)\n\ts_barrier" ::: "memory");
}

// Wx layout: Wx[v][u*4 + nt], u = h-unit 0..255, nt in {i,f,g,o}; oj = nt*256+u.

// ---------------------------------------------------------------------------
// K1: Wx[v][u*4+nt] = bf16( b_ih[oj] + b_hh[oj] + emb[v] . W_ih[oj] )
// ---------------------------------------------------------------------------
__global__ __launch_bounds__(256) void wx_k1(
    const float* __restrict__ emb, const float* __restrict__ Wih,
    const float* __restrict__ bih, const float* __restrict__ bhh,
    unsigned short* __restrict__ Wx) {
  const int vb = blockIdx.x * 16;
  const int w1 = threadIdx.x >> 6, lane = threadIdx.x & 63;
  const int quad = lane >> 4, n = lane & 15;
  const int combo = blockIdx.y * 4 + w1;        // 0..15 -> units combo*16..+15

  float bias[4];
  short8 bfr[4][4];
#pragma unroll
  for (int nt = 0; nt < 4; ++nt) {
    const int oj = nt * 256 + combo * 16 + n;
    bias[nt] = bih[oj] + bhh[oj];
#pragma unroll
    for (int kc = 0; kc < 4; ++kc) {
      const f32x4* wp = (const f32x4*)(Wih + (size_t)oj * EMBD + kc * 32 + quad * 8);
      bfr[nt][kc] = pack2(wp[0], wp[1]);
    }
  }
  short8 af[4];
#pragma unroll
  for (int kc = 0; kc < 4; ++kc) {
    const f32x4* ep = (const f32x4*)(emb + (size_t)(vb + n) * EMBD + kc * 32 + quad * 8);
    af[kc] = pack2(ep[0], ep[1]);
  }
  f32x4 acc[4];
#pragma unroll
  for (int nt = 0; nt < 4; ++nt) acc[nt] = (f32x4){0.f, 0.f, 0.f, 0.f};
#pragma unroll
  for (int kc = 0; kc < 4; ++kc)
#pragma unroll
    for (int nt = 0; nt < 4; ++nt)
      acc[nt] = __builtin_amdgcn_mfma_f32_16x16x32_bf16(af[kc], bfr[nt][kc], acc[nt], 0, 0, 0);
#pragma unroll
  for (int rr = 0; rr < 4; ++rr) {
    ushort4_t o;
#pragma unroll
    for (int nt = 0; nt < 4; ++nt) o[nt] = f2bf(acc[nt][rr] + bias[nt]);
    *(ushort4_t*)&Wx[(size_t)(vb + quad * 4 + rr) * G4 + (combo * 16 + n) * 4] = o;
  }
}

// ---------------------------------------------------------------------------
// K2: self-contained LSTM recurrence (best-known structure, R4) + LDS-only
// barrier + register-held last-h. 16 WGs x 512 threads; WG = 16 batch rows,
// ALL 256 h-units -> zero cross-WG traffic, ONE barrier per step.
// W_hh split: K-chunks 0..5 in VGPRs (192/lane), chunks 6..7 in LDS (128 KB).
// Wave w owns units [w*32,(w+1)*32) as two half-passes gl=0,1 (acc stays 16).
// All register arrays indexed by unrolled constants only (round-1 lesson).
// NO global stores inside the loop; no LDS-shared data fed by global loads.
// ---------------------------------------------------------------------------
__global__ __launch_bounds__(512, 2) void lstm_k2(
    const int* __restrict__ x, const float* __restrict__ Whh,
    const unsigned short* __restrict__ Wx,
    float* __restrict__ lastH) {               // [256][256]
  const int group = blockIdx.x;                // 16 groups of 16 batch rows
  const int rowbase = group * 16;
  const int tid = threadIdx.x;
  const int w = tid >> 6, lane = tid & 63;
  const int quad = lane >> 4, n = lane & 15;

  __shared__ __attribute__((aligned(16))) unsigned short h_lds[2][16][264];   // 16.5 KB
  __shared__ __attribute__((aligned(16))) unsigned short wlds[8][2][4][2][64][8]; // 128 KB
  __shared__ int zpos[16];

  if (tid < 16) zpos[tid] = 1 << 30;
  __syncthreads();
  // scan tokens for the pad position (first zero)
  for (int i = tid; i < 16 * TSEQ; i += 512) {
    const int row = i >> 9, tc = i & 511;
    if (x[(size_t)(rowbase + row) * TSEQ + tc] == 0) atomicMin(&zpos[row], tc);
  }
  // zero h(0) (buffer 0)
  for (int i = tid; i < 16 * 264; i += 512) ((unsigned short*)h_lds)[i] = 0;

  // fill LDS weights (K-chunks 6,7) for this wave's 8 n-tiles
#pragma unroll
  for (int gl = 0; gl < 2; ++gl)
#pragma unroll
    for (int nt = 0; nt < 4; ++nt)
#pragma unroll
      for (int kcl = 0; kcl < 2; ++kcl) {
        const int oj = nt * 256 + (2 * w + gl) * 16 + n;
        const f32x4* wp = (const f32x4*)(Whh + (size_t)oj * HID + (6 + kcl) * 32 + quad * 8);
        *(short8*)&wlds[w][gl][nt][kcl][lane][0] = pack2(wp[0], wp[1]);
      }

  // register weights: K-chunks 0..5.  B[k][col=n] = Whh[oj(n)][k].
  short8 bfr[2][4][6];
#pragma unroll
  for (int gl = 0; gl < 2; ++gl)
#pragma unroll
    for (int nt = 0; nt < 4; ++nt) {
      const int oj = nt * 256 + (2 * w + gl) * 16 + n;
      const float* wrow = Whh + (size_t)oj * HID;
#pragma unroll
      for (int kc = 0; kc < 6; ++kc) {
        const f32x4* wp = (const f32x4*)(wrow + kc * 32 + quad * 8);
        bfr[gl][nt][kc] = pack2(wp[0], wp[1]);
      }
    }

  float cst[2][4];
  float lastreg[2][4];
#pragma unroll
  for (int gl = 0; gl < 2; ++gl)
#pragma unroll
    for (int rr = 0; rr < 4; ++rr) { cst[gl][rr] = 0.f; lastreg[gl][rr] = 0.f; }

  __syncthreads();   // zpos, h(0), wlds ready
  int idx4[4];
#pragma unroll
  for (int rr = 0; rr < 4; ++rr) idx4[rr] = zpos[quad * 4 + rr] - 1;

  // initial Wx load (t=0) + token prefetch for t=1
  ushort4_t wxbuf[2][4];
  int tokc[4];
#pragma unroll
  for (int rr = 0; rr < 4; ++rr) {
    const int t0 = x[(size_t)(rowbase + quad * 4 + rr) * TSEQ + 0];
#pragma unroll
    for (int gl = 0; gl < 2; ++gl)
      wxbuf[gl][rr] = *(const ushort4_t*)(Wx + (size_t)t0 * G4 + ((2 * w + gl) * 16 + n) * 4);
    tokc[rr] = x[(size_t)(rowbase + quad * 4 + rr) * TSEQ + 1];
  }

  for (int t = 0; t < TSEQ; ++t) {
    const int p = t & 1, pn = p ^ 1;
    const int tnn = (t + 2 < TSEQ) ? (t + 2) : (TSEQ - 1);

#pragma unroll
    for (int gl = 0; gl < 2; ++gl) {
      // acc init from prefetched Wx (has both biases)
      f32x4 acc[4];
#pragma unroll
      for (int rr = 0; rr < 4; ++rr) {
        const ushort4_t g4 = wxbuf[gl][rr];
#pragma unroll
        for (int nt = 0; nt < 4; ++nt) acc[nt][rr] = bf2f(g4[nt]);
      }
      // immediately re-issue prefetch for t+1 (token was prefetched last step);
      // consumed next step -> full-step latency overlap (no drain at barrier now)
#pragma unroll
      for (int rr = 0; rr < 4; ++rr)
        wxbuf[gl][rr] = *(const ushort4_t*)(Wx + (size_t)tokc[rr] * G4 + ((2 * w + gl) * 16 + n) * 4);

      // GEMM: K-chunks 0..5 from register B-frags
#pragma unroll
      for (int kc = 0; kc < 6; ++kc) {
        const short8 a = *(const short8*)&h_lds[p][n][kc * 32 + quad * 8];
#pragma unroll
        for (int nt = 0; nt < 4; ++nt)
          acc[nt] = __builtin_amdgcn_mfma_f32_16x16x32_bf16(a, bfr[gl][nt][kc], acc[nt], 0, 0, 0);
      }
      // K-chunks 6..7 from LDS B-frags
#pragma unroll
      for (int kcl = 0; kcl < 2; ++kcl) {
        const short8 a = *(const short8*)&h_lds[p][n][(6 + kcl) * 32 + quad * 8];
#pragma unroll
        for (int nt = 0; nt < 4; ++nt) {
          const short8 b = *(const short8*)&wlds[w][gl][nt][kcl][lane][0];
          acc[nt] = __builtin_amdgcn_mfma_f32_16x16x32_bf16(a, b, acc[nt], 0, 0, 0);
        }
      }
      // pointwise: lane owns unit u=(2w+gl)*16+n for rows quad*4+rr
      const int u = (2 * w + gl) * 16 + n;
#pragma unroll
      for (int rr = 0; rr < 4; ++rr) {
        const float gi = acc[0][rr], gf = acc[1][rr], gg = acc[2][rr], go = acc[3][rr];
        const float ci = sigmoid_(gf) * cst[gl][rr] + sigmoid_(gi) * tanh_(gg);
        cst[gl][rr] = ci;
        const float hv = sigmoid_(go) * tanh_(ci);
        h_lds[pn][quad * 4 + rr][u] = f2bf(hv);
        lastreg[gl][rr] = (t == idx4[rr]) ? hv : lastreg[gl][rr];  // no global store
      }
    }
    // token prefetch for t+2
#pragma unroll
    for (int rr = 0; rr < 4; ++rr)
      tokc[rr] = x[(size_t)(rowbase + quad * 4 + rr) * TSEQ + tnn];

    barrier_lds_only();  // h(t+1) complete; global prefetches stay in flight
  }

  // final: write gathered last-valid h (f32, pre-bf16-rounding)
#pragma unroll
  for (int gl = 0; gl < 2; ++gl) {
    const int u = (2 * w + gl) * 16 + n;
#pragma unroll
    for (int rr = 0; rr < 4; ++rr)
      lastH[(size_t)(rowbase + quad * 4 + rr) * HID + u] = lastreg[gl][rr];
  }
}

// ---------------------------------------------------------------------------
// K3: logits + softmax. One wave per batch row; lane j = output j.
// ---------------------------------------------------------------------------
__global__ __launch_bounds__(64) void head_k3(
    const float* __restrict__ lastH, const float* __restrict__ Wout,
    const float* __restrict__ bout, float* __restrict__ out) {
  const int b = blockIdx.x, j = threadIdx.x;
  const f32x4* hv = (const f32x4*)(lastH + (size_t)b * HID);
  const f32x4* wv = (const f32x4*)(Wout + (size_t)j * HID);
  float acc = bout[j];
#pragma unroll 8
  for (int k = 0; k < HID / 4; ++k) {
    const f32x4 a = hv[k], ww = wv[k];
    acc += a[0] * ww[0] + a[1] * ww[1] + a[2] * ww[2] + a[3] * ww[3];
  }
  float m = acc;
  for (int s = 32; s > 0; s >>= 1) m = fmaxf(m, __shfl_xor(m, s, 64));
  const float e = __expf(acc - m);
  float ssum = e;
  for (int s = 32; s > 0; s >>= 1) ssum += __shfl_xor(ssum, s, 64);
  out[(size_t)b * OUTD + j] = e / ssum;
}

// ---------------------------------------------------------------------------
extern "C" void kernel_launch(void* const* d_in, const int* in_sizes, int n_in,
                              void* d_out, int out_size, void* d_ws, size_t ws_size,
                              hipStream_t stream) {
  const int*   x    = (const int*)d_in[0];
  const float* emb  = (const float*)d_in[1];
  const float* Wih  = (const float*)d_in[2];
  const float* Whh  = (const float*)d_in[3];
  const float* bih  = (const float*)d_in[4];
  const float* bhh  = (const float*)d_in[5];
  const float* Wout = (const float*)d_in[6];
  const float* bout = (const float*)d_in[7];
  float* out = (float*)d_out;

  // workspace carve (~97.9 MiB)
  char* ws = (char*)d_ws;
  unsigned short* Wx = (unsigned short*)ws;                 // 102,400,000 B
  float* lastH = (float*)(ws + 102400000);                  // 262,144 B

  hipLaunchKernelGGL(wx_k1, dim3(3125, 4), dim3(256), 0, stream,
                     emb, Wih, bih, bhh, Wx);
  hipLaunchKernelGGL(lstm_k2, dim3(16), dim3(512), 0, stream,
                     x, Whh, Wx, lastH);
  hipLaunchKernelGGL(head_k3, dim3(BATCH), dim3(OUTD), 0, stream,
                     lastH, Wout, bout, out);
}